// Round 7
// baseline (573.714 us; speedup 1.0000x reference)
//
#include <hip/hip_runtime.h>
#include <hip/hip_bf16.h>

// ---------------------------------------------------------------------------
// GINE x2 + mean-pool + FC.  CSR-gather, bf16-packed edge attrs, wave-per-node
// barrier-free convs, MLPs via transposed-LDS weights (b128) + readlane
// broadcast (no LDS staging of activations).  [resubmit: rounds 4/5 hit a
// dead container; no kernel-side failure mechanism found]
// ---------------------------------------------------------------------------

#define CHUNK 1024

__device__ __forceinline__ float bf2f(unsigned short u) {
  return __uint_as_float(((unsigned)u) << 16);
}
__device__ __forceinline__ int rdlane_i(int v, int l) {
  return __builtin_amdgcn_readlane(v, l);
}
__device__ __forceinline__ float rdlane_f(float v, int l) {
  return __uint_as_float(
      (unsigned)__builtin_amdgcn_readlane((int)__float_as_uint(v), l));
}
__device__ __forceinline__ unsigned short f2bf(float f) {
  __hip_bfloat16 hb = __float2bfloat16(f);
  return *reinterpret_cast<unsigned short*>(&hb);
}

__global__ __launch_bounds__(256) void hist_kernel(
    const int* __restrict__ dstIdx, int* __restrict__ deg, int E) {
  int i = blockIdx.x * 256 + threadIdx.x;
  int e0 = i * 4;
  if (e0 + 3 < E) {
    int4 d = reinterpret_cast<const int4*>(dstIdx)[i];
    atomicAdd(&deg[d.x], 1);
    atomicAdd(&deg[d.y], 1);
    atomicAdd(&deg[d.z], 1);
    atomicAdd(&deg[d.w], 1);
  } else {
    for (int e = e0; e < E; ++e) atomicAdd(&deg[dstIdx[e]], 1);
  }
}

__global__ __launch_bounds__(256) void scan1_kernel(
    const int* __restrict__ deg, int* __restrict__ cursor,
    int* __restrict__ blockSum, int N) {
  __shared__ int sd[256];
  int t = threadIdx.x;
  int base = blockIdx.x * CHUNK + t * 4;
  int v0 = (base + 0 < N) ? deg[base + 0] : 0;
  int v1 = (base + 1 < N) ? deg[base + 1] : 0;
  int v2 = (base + 2 < N) ? deg[base + 2] : 0;
  int v3 = (base + 3 < N) ? deg[base + 3] : 0;
  int ts = v0 + v1 + v2 + v3;
  sd[t] = ts;
  __syncthreads();
  for (int off = 1; off < 256; off <<= 1) {
    int xv = (t >= off) ? sd[t - off] : 0;
    __syncthreads();
    sd[t] += xv;
    __syncthreads();
  }
  int excl = sd[t] - ts;
  if (t == 255) blockSum[blockIdx.x] = sd[255];
  if (base + 0 < N) cursor[base + 0] = excl;
  if (base + 1 < N) cursor[base + 1] = excl + v0;
  if (base + 2 < N) cursor[base + 2] = excl + v0 + v1;
  if (base + 3 < N) cursor[base + 3] = excl + v0 + v1 + v2;
}

__global__ __launch_bounds__(256) void scan2_kernel(
    const int* __restrict__ blockSum, int* __restrict__ blockOff, int nb) {
  __shared__ int sd[256];
  int t = threadIdx.x;
  int base = t * 4;
  int v0 = (base + 0 < nb) ? blockSum[base + 0] : 0;
  int v1 = (base + 1 < nb) ? blockSum[base + 1] : 0;
  int v2 = (base + 2 < nb) ? blockSum[base + 2] : 0;
  int v3 = (base + 3 < nb) ? blockSum[base + 3] : 0;
  int ts = v0 + v1 + v2 + v3;
  sd[t] = ts;
  __syncthreads();
  for (int off = 1; off < 256; off <<= 1) {
    int xv = (t >= off) ? sd[t - off] : 0;
    __syncthreads();
    sd[t] += xv;
    __syncthreads();
  }
  int excl = sd[t] - ts;
  if (base + 0 < nb) blockOff[base + 0] = excl;
  if (base + 1 < nb) blockOff[base + 1] = excl + v0;
  if (base + 2 < nb) blockOff[base + 2] = excl + v0 + v1;
  if (base + 3 < nb) blockOff[base + 3] = excl + v0 + v1 + v2;
}

__global__ __launch_bounds__(256) void scan3_kernel(
    int* __restrict__ cursor, const int* __restrict__ blockOff, int N) {
  int i = blockIdx.x * 256 + threadIdx.x;
  if (i < N) cursor[i] += blockOff[i >> 10];  // log2(CHUNK)
}

__global__ __launch_bounds__(256) void scatter_kernel(
    const int* __restrict__ srcIdx, const int* __restrict__ dstIdx,
    const float* __restrict__ ea, int* __restrict__ cursor,
    int* __restrict__ csr_src, uint2* __restrict__ csr_ea8, int E) {
  int e = blockIdx.x * 256 + threadIdx.x;
  if (e >= E) return;
  float4 a = reinterpret_cast<const float4*>(ea)[e];
  uint2 u;
  u.x = (unsigned)f2bf(a.x) | ((unsigned)f2bf(a.y) << 16);
  u.y = (unsigned)f2bf(a.z) | ((unsigned)f2bf(a.w) << 16);
  int pos = atomicAdd(&cursor[dstIdx[e]], 1);
  csr_src[pos] = srcIdx[e];
  csr_ea8[pos] = u;
}

// Fused conv1 + MLP1.  One wave per node; lanes process edges in parallel,
// 7-channel butterfly reduce; MLP layerA via small LDS, layerB via WbT b128 +
// readlane.  No inter-wave barriers after weight staging.
__global__ __launch_bounds__(512) void conv1_mlp1_kernel(
    const float* __restrict__ x, const int* __restrict__ csr_src,
    const uint2* __restrict__ csr_ea8, const float* __restrict__ We1,
    const float* __restrict__ be1, const int* __restrict__ deg,
    const int* __restrict__ cursor, const float* __restrict__ W1a,
    const float* __restrict__ b1a, const float* __restrict__ W1b,
    const float* __restrict__ b1b, unsigned short* __restrict__ h1b, int N) {
  __shared__ float sWa[7 * 64];
  __shared__ float sWbT[64 * 68];
  for (int i = threadIdx.x; i < 7 * 64; i += 512) sWa[i] = W1a[i];
  for (int i = threadIdx.x; i < 64 * 64; i += 512)
    sWbT[(i & 63) * 68 + (i >> 6)] = W1b[i];
  __syncthreads();
  int w = threadIdx.x >> 6, j = threadIdx.x & 63;
  float vba = b1a[j], vbb = b1b[j];
  float we[28], be[7];
#pragma unroll
  for (int i = 0; i < 28; ++i) we[i] = We1[i];  // uniform -> SGPR
#pragma unroll
  for (int i = 0; i < 7; ++i) be[i] = be1[i];
  int wid = blockIdx.x * 8 + w;
  int nw = gridDim.x * 8;
  for (int n = wid; n < N; n += nw) {
    int end = cursor[n];
    int start = end - deg[n];
    float acc[7] = {0.f, 0.f, 0.f, 0.f, 0.f, 0.f, 0.f};
    for (int i = start + j; i < end; i += 64) {
      int s = csr_src[i];
      uint2 u = csr_ea8[i];
      float a0 = __uint_as_float(u.x << 16);
      float a1 = __uint_as_float(u.x & 0xffff0000u);
      float a2 = __uint_as_float(u.y << 16);
      float a3 = __uint_as_float(u.y & 0xffff0000u);
      const float* xs = x + (size_t)s * 7;
#pragma unroll
      for (int c = 0; c < 7; ++c) {
        float v = be[c] + a0 * we[c] + a1 * we[7 + c] + a2 * we[14 + c] +
                  a3 * we[21 + c] + xs[c];
        acc[c] += fmaxf(v, 0.f);
      }
    }
#pragma unroll
    for (int c = 0; c < 7; ++c) {
#pragma unroll
      for (int m = 1; m < 64; m <<= 1) acc[c] += __shfl_xor(acc[c], m);
    }
    const float* xn = x + (size_t)n * 7;  // uniform -> s_load
    float p[7];
#pragma unroll
    for (int c = 0; c < 7; ++c) p[c] = acc[c] + xn[c];
    // layer A: t_j = ba_j + sum_c p_c * Wa[c][j]
    float t = vba;
#pragma unroll
    for (int c = 0; c < 7; ++c) t += p[c] * sWa[c * 64 + j];
    t = fmaxf(t, 0.f);
    // layer B: h_j = bb_j + sum_k t_k * Wb[k][j]  (WbT b128 + readlane)
    float h0 = vbb, h1 = 0.f, h2 = 0.f, h3 = 0.f;
#pragma unroll
    for (int kq = 0; kq < 16; ++kq) {
      const float4 wv =
          *reinterpret_cast<const float4*>(&sWbT[j * 68 + kq * 4]);
      h0 += rdlane_f(t, kq * 4 + 0) * wv.x;
      h1 += rdlane_f(t, kq * 4 + 1) * wv.y;
      h2 += rdlane_f(t, kq * 4 + 2) * wv.z;
      h3 += rdlane_f(t, kq * 4 + 3) * wv.w;
    }
    float h = fmaxf(h0 + h1 + h2 + h3, 0.f);
    h1b[(size_t)n * 64 + j] = f2bf(h);
  }
}

// Fused conv2 + MLP2.  Wave per node, lane = channel.  Edge {src, ea}
// lane-parallel loads broadcast via readlane (constant lane index).
__global__ __launch_bounds__(512) void conv2_mlp2_kernel(
    const unsigned short* __restrict__ h1b, const int* __restrict__ csr_src,
    const uint2* __restrict__ csr_ea8, const int* __restrict__ deg,
    const int* __restrict__ cursor, const float* __restrict__ We2,
    const float* __restrict__ be2, const float* __restrict__ W2a,
    const float* __restrict__ b2a, const float* __restrict__ W2b,
    const float* __restrict__ b2b, unsigned short* __restrict__ h2b, int N) {
  __shared__ float sWaT[64 * 68];
  __shared__ float sWbT[64 * 68];
  for (int i = threadIdx.x; i < 4096; i += 512) {
    sWaT[(i & 63) * 68 + (i >> 6)] = W2a[i];
    sWbT[(i & 63) * 68 + (i >> 6)] = W2b[i];
  }
  __syncthreads();
  int w = threadIdx.x >> 6, j = threadIdx.x & 63;
  float vba = b2a[j], vbb = b2b[j];
  float w0 = We2[j], w1 = We2[64 + j], w2 = We2[128 + j], w3 = We2[192 + j];
  float bej = be2[j];
  int wid = blockIdx.x * 8 + w;
  int nw = gridDim.x * 8;
  for (int n = wid; n < N; n += nw) {
    int end = cursor[n];
    int start = end - deg[n];
    float acc0 = 0.f, acc1 = 0.f;
    for (int base = start; base < end; base += 64) {
      int cnt = min(64, end - base);
      int sl = 0;
      unsigned ax = 0, ay = 0;
      if (base + j < end) {
        sl = csr_src[base + j];
        uint2 u = csr_ea8[base + j];
        ax = u.x;
        ay = u.y;
      }
#pragma unroll
      for (int gq = 0; gq < 16; ++gq) {
        if (gq * 4 < cnt) {  // wave-uniform branch
#pragma unroll
          for (int tt = 0; tt < 4; ++tt) {
            int ii = gq * 4 + tt;
            if (ii < cnt) {  // wave-uniform
              int s = rdlane_i(sl, ii);
              unsigned uax = (unsigned)rdlane_i((int)ax, ii);
              unsigned uay = (unsigned)rdlane_i((int)ay, ii);
              float a0 = __uint_as_float(uax << 16);
              float a1 = __uint_as_float(uax & 0xffff0000u);
              float a2 = __uint_as_float(uay << 16);
              float a3 = __uint_as_float(uay & 0xffff0000u);
              float e2 = bej + a0 * w0 + a1 * w1 + a2 * w2 + a3 * w3;
              float v = bf2f(h1b[(size_t)s * 64 + j]);
              if (tt & 1)
                acc1 += fmaxf(v + e2, 0.f);
              else
                acc0 += fmaxf(v + e2, 0.f);
            }
          }
        }
      }
    }
    float p = bf2f(h1b[(size_t)n * 64 + j]) + acc0 + acc1;
    // layer A
    float t0 = vba, t1 = 0.f, t2 = 0.f, t3 = 0.f;
#pragma unroll
    for (int kq = 0; kq < 16; ++kq) {
      const float4 wv =
          *reinterpret_cast<const float4*>(&sWaT[j * 68 + kq * 4]);
      t0 += rdlane_f(p, kq * 4 + 0) * wv.x;
      t1 += rdlane_f(p, kq * 4 + 1) * wv.y;
      t2 += rdlane_f(p, kq * 4 + 2) * wv.z;
      t3 += rdlane_f(p, kq * 4 + 3) * wv.w;
    }
    float t = fmaxf(t0 + t1 + t2 + t3, 0.f);
    // layer B
    float h0 = vbb, h1 = 0.f, h2 = 0.f, h3 = 0.f;
#pragma unroll
    for (int kq = 0; kq < 16; ++kq) {
      const float4 wv =
          *reinterpret_cast<const float4*>(&sWbT[j * 68 + kq * 4]);
      h0 += rdlane_f(t, kq * 4 + 0) * wv.x;
      h1 += rdlane_f(t, kq * 4 + 1) * wv.y;
      h2 += rdlane_f(t, kq * 4 + 2) * wv.z;
      h3 += rdlane_f(t, kq * 4 + 3) * wv.w;
    }
    float h = fmaxf(h0 + h1 + h2 + h3, 0.f);
    h2b[(size_t)n * 64 + j] = f2bf(h);
  }
}

__global__ __launch_bounds__(64) void pool_fc_kernel(
    const unsigned short* __restrict__ h2b, const int* __restrict__ batch,
    const float* __restrict__ Wfc, const float* __restrict__ bfc,
    float* __restrict__ out, int N, int G) {
  int g = blockIdx.x;
  int j = threadIdx.x;  // 0..63
  int lo = 0, hi = N;
  while (lo < hi) {
    int mid = (lo + hi) >> 1;
    if (batch[mid] < g) lo = mid + 1; else hi = mid;
  }
  int start = lo;
  lo = start; hi = N;
  while (lo < hi) {
    int mid = (lo + hi) >> 1;
    if (batch[mid] < g + 1) lo = mid + 1; else hi = mid;
  }
  int end = lo;
  float s = 0.f;
  for (int r = start; r < end; ++r) s += bf2f(h2b[(size_t)r * 64 + j]);
  float cnt = (float)(end - start);
  float pooled = s / fmaxf(cnt, 1.f);
  __shared__ float spool[64];
  spool[j] = pooled;
  __syncthreads();
  if (j < 12) {
    float o = bfc[j];
#pragma unroll
    for (int k = 0; k < 64; ++k) o += spool[k] * Wfc[k * 12 + j];
    out[(size_t)g * 12 + j] = o;
  }
}

extern "C" void kernel_launch(void* const* d_in, const int* in_sizes, int n_in,
                              void* d_out, int out_size, void* d_ws,
                              size_t ws_size, hipStream_t stream) {
  const float* x   = (const float*)d_in[0];
  const float* ea  = (const float*)d_in[1];
  const float* We1 = (const float*)d_in[2];
  const float* be1 = (const float*)d_in[3];
  const float* We2 = (const float*)d_in[4];
  const float* be2 = (const float*)d_in[5];
  const float* W1a = (const float*)d_in[6];
  const float* b1a = (const float*)d_in[7];
  const float* W1b = (const float*)d_in[8];
  const float* b1b = (const float*)d_in[9];
  const float* W2a = (const float*)d_in[10];
  const float* b2a = (const float*)d_in[11];
  const float* W2b = (const float*)d_in[12];
  const float* b2b = (const float*)d_in[13];
  const float* Wfc = (const float*)d_in[14];
  const float* bfc = (const float*)d_in[15];
  const int* eidx  = (const int*)d_in[16];
  const int* batch = (const int*)d_in[17];

  int N = in_sizes[0] / 7;
  int E = in_sizes[1] / 4;
  int G = out_size / 12;
  const int* srcIdx = eidx;
  const int* dstIdx = eidx + E;

  char* ws = (char*)d_ws;
  int*    deg      = (int*)ws;            ws += (size_t)N * 4;
  int*    cursor   = (int*)ws;            ws += (size_t)N * 4;
  int*    blockSum = (int*)ws;            ws += 4096;
  int*    blockOff = (int*)ws;            ws += 4096;
  int*    csr_src  = (int*)ws;            ws += (size_t)E * 4;
  uint2*  csr_ea8  = (uint2*)ws;          ws += (size_t)E * 8;
  unsigned short* h1b = (unsigned short*)ws; ws += (size_t)N * 64 * 2;
  unsigned short* h2b = (unsigned short*)ws; /* += N*64*2 */
  // total ~ 0.8 + 6.4 + 12.8 + 12.8 + 12.8 MB ~= 46 MB

  int nb = (N + CHUNK - 1) / CHUNK;

  hipMemsetAsync(deg, 0, (size_t)N * 4, stream);
  hist_kernel<<<((E + 3) / 4 + 255) / 256, 256, 0, stream>>>(dstIdx, deg, E);
  scan1_kernel<<<nb, 256, 0, stream>>>(deg, cursor, blockSum, N);
  scan2_kernel<<<1, 256, 0, stream>>>(blockSum, blockOff, nb);
  scan3_kernel<<<(N + 255) / 256, 256, 0, stream>>>(cursor, blockOff, N);
  scatter_kernel<<<(E + 255) / 256, 256, 0, stream>>>(srcIdx, dstIdx, ea,
                                                      cursor, csr_src, csr_ea8,
                                                      E);
  conv1_mlp1_kernel<<<1024, 512, 0, stream>>>(x, csr_src, csr_ea8, We1, be1,
                                              deg, cursor, W1a, b1a, W1b, b1b,
                                              h1b, N);
  conv2_mlp2_kernel<<<1024, 512, 0, stream>>>(h1b, csr_src, csr_ea8, deg,
                                              cursor, We2, be2, W2a, b2a, W2b,
                                              b2b, h2b, N);
  pool_fc_kernel<<<G, 64, 0, stream>>>(h2b, batch, Wfc, bfc, (float*)d_out, N,
                                       G);
}

// Round 9
// 443.098 us; speedup vs baseline: 1.2948x; 1.2948x over previous
//
#include <hip/hip_runtime.h>
#include <hip/hip_bf16.h>

// ---------------------------------------------------------------------------
// GINE x2 + mean-pool + FC.  CSR-gather (uint4 entries: src + bf16x4 ea),
// conv2 processes 4 edges/wave-iteration (quarter-parallel ushort4 gathers),
// MLPs via transposed-LDS weights (b128) + readlane broadcast.
// [resubmit: round 8 hit the same dead container as rounds 4-6]
// ---------------------------------------------------------------------------

#define CHUNK 1024

__device__ __forceinline__ float bf2f(unsigned short u) {
  return __uint_as_float(((unsigned)u) << 16);
}
__device__ __forceinline__ float rdlane_f(float v, int l) {
  return __uint_as_float(
      (unsigned)__builtin_amdgcn_readlane((int)__float_as_uint(v), l));
}
__device__ __forceinline__ unsigned short f2bf(float f) {
  __hip_bfloat16 hb = __float2bfloat16(f);
  return *reinterpret_cast<unsigned short*>(&hb);
}

__global__ __launch_bounds__(256) void hist_kernel(
    const int* __restrict__ dstIdx, int* __restrict__ deg, int E) {
  int i = blockIdx.x * 256 + threadIdx.x;
  int e0 = i * 4;
  if (e0 + 3 < E) {
    int4 d = reinterpret_cast<const int4*>(dstIdx)[i];
    atomicAdd(&deg[d.x], 1);
    atomicAdd(&deg[d.y], 1);
    atomicAdd(&deg[d.z], 1);
    atomicAdd(&deg[d.w], 1);
  } else {
    for (int e = e0; e < E; ++e) atomicAdd(&deg[dstIdx[e]], 1);
  }
}

__global__ __launch_bounds__(256) void scan1_kernel(
    const int* __restrict__ deg, int* __restrict__ cursor,
    int* __restrict__ blockSum, int N) {
  __shared__ int sd[256];
  int t = threadIdx.x;
  int base = blockIdx.x * CHUNK + t * 4;
  int v0 = (base + 0 < N) ? deg[base + 0] : 0;
  int v1 = (base + 1 < N) ? deg[base + 1] : 0;
  int v2 = (base + 2 < N) ? deg[base + 2] : 0;
  int v3 = (base + 3 < N) ? deg[base + 3] : 0;
  int ts = v0 + v1 + v2 + v3;
  sd[t] = ts;
  __syncthreads();
  for (int off = 1; off < 256; off <<= 1) {
    int xv = (t >= off) ? sd[t - off] : 0;
    __syncthreads();
    sd[t] += xv;
    __syncthreads();
  }
  int excl = sd[t] - ts;
  if (t == 255) blockSum[blockIdx.x] = sd[255];
  if (base + 0 < N) cursor[base + 0] = excl;
  if (base + 1 < N) cursor[base + 1] = excl + v0;
  if (base + 2 < N) cursor[base + 2] = excl + v0 + v1;
  if (base + 3 < N) cursor[base + 3] = excl + v0 + v1 + v2;
}

__global__ __launch_bounds__(256) void scan2_kernel(
    const int* __restrict__ blockSum, int* __restrict__ blockOff, int nb) {
  __shared__ int sd[256];
  int t = threadIdx.x;
  int base = t * 4;
  int v0 = (base + 0 < nb) ? blockSum[base + 0] : 0;
  int v1 = (base + 1 < nb) ? blockSum[base + 1] : 0;
  int v2 = (base + 2 < nb) ? blockSum[base + 2] : 0;
  int v3 = (base + 3 < nb) ? blockSum[base + 3] : 0;
  int ts = v0 + v1 + v2 + v3;
  sd[t] = ts;
  __syncthreads();
  for (int off = 1; off < 256; off <<= 1) {
    int xv = (t >= off) ? sd[t - off] : 0;
    __syncthreads();
    sd[t] += xv;
    __syncthreads();
  }
  int excl = sd[t] - ts;
  if (base + 0 < nb) blockOff[base + 0] = excl;
  if (base + 1 < nb) blockOff[base + 1] = excl + v0;
  if (base + 2 < nb) blockOff[base + 2] = excl + v0 + v1;
  if (base + 3 < nb) blockOff[base + 3] = excl + v0 + v1 + v2;
}

__global__ __launch_bounds__(256) void scan3_kernel(
    int* __restrict__ cursor, const int* __restrict__ blockOff, int N) {
  int i = blockIdx.x * 256 + threadIdx.x;
  if (i < N) cursor[i] += blockOff[i >> 10];  // log2(CHUNK)
}

__global__ __launch_bounds__(256) void scatter_kernel(
    const int* __restrict__ srcIdx, const int* __restrict__ dstIdx,
    const float* __restrict__ ea, int* __restrict__ cursor,
    uint4* __restrict__ csr, int E) {
  int e = blockIdx.x * 256 + threadIdx.x;
  if (e >= E) return;
  float4 a = reinterpret_cast<const float4*>(ea)[e];
  uint4 v;
  v.x = (unsigned)srcIdx[e];
  v.y = (unsigned)f2bf(a.x) | ((unsigned)f2bf(a.y) << 16);
  v.z = (unsigned)f2bf(a.z) | ((unsigned)f2bf(a.w) << 16);
  v.w = 0;
  int pos = atomicAdd(&cursor[dstIdx[e]], 1);
  csr[pos] = v;  // single 16B scattered store
}

// Fused conv1 + MLP1.  One wave per node; lanes process edges in parallel
// (lane = edge), 7-channel butterfly reduce; layerA via small LDS, layerB via
// WbT b128 + readlane.  No inter-wave barriers after weight staging.
__global__ __launch_bounds__(512) void conv1_mlp1_kernel(
    const float* __restrict__ x, const uint4* __restrict__ csr,
    const float* __restrict__ We1, const float* __restrict__ be1,
    const int* __restrict__ deg, const int* __restrict__ cursor,
    const float* __restrict__ W1a, const float* __restrict__ b1a,
    const float* __restrict__ W1b, const float* __restrict__ b1b,
    unsigned short* __restrict__ h1b, int N) {
  __shared__ float sWa[7 * 64];
  __shared__ float sWbT[64 * 68];
  for (int i = threadIdx.x; i < 7 * 64; i += 512) sWa[i] = W1a[i];
  for (int i = threadIdx.x; i < 64 * 64; i += 512)
    sWbT[(i & 63) * 68 + (i >> 6)] = W1b[i];
  __syncthreads();
  int w = threadIdx.x >> 6, j = threadIdx.x & 63;
  float vba = b1a[j], vbb = b1b[j];
  float we[28], be[7];
#pragma unroll
  for (int i = 0; i < 28; ++i) we[i] = We1[i];  // uniform -> SGPR
#pragma unroll
  for (int i = 0; i < 7; ++i) be[i] = be1[i];
  int wid = blockIdx.x * 8 + w;
  int nw = gridDim.x * 8;
  for (int n = wid; n < N; n += nw) {
    int end = cursor[n];
    int start = end - deg[n];
    float acc[7] = {0.f, 0.f, 0.f, 0.f, 0.f, 0.f, 0.f};
    for (int i = start + j; i < end; i += 64) {
      uint4 u = csr[i];
      int s = (int)u.x;
      float a0 = __uint_as_float(u.y << 16);
      float a1 = __uint_as_float(u.y & 0xffff0000u);
      float a2 = __uint_as_float(u.z << 16);
      float a3 = __uint_as_float(u.z & 0xffff0000u);
      const float* xs = x + (size_t)s * 7;
#pragma unroll
      for (int c = 0; c < 7; ++c) {
        float v = be[c] + a0 * we[c] + a1 * we[7 + c] + a2 * we[14 + c] +
                  a3 * we[21 + c] + xs[c];
        acc[c] += fmaxf(v, 0.f);
      }
    }
#pragma unroll
    for (int c = 0; c < 7; ++c) {
#pragma unroll
      for (int m = 1; m < 64; m <<= 1) acc[c] += __shfl_xor(acc[c], m);
    }
    const float* xn = x + (size_t)n * 7;  // uniform -> s_load
    float p[7];
#pragma unroll
    for (int c = 0; c < 7; ++c) p[c] = acc[c] + xn[c];
    float t = vba;
#pragma unroll
    for (int c = 0; c < 7; ++c) t += p[c] * sWa[c * 64 + j];
    t = fmaxf(t, 0.f);
    float h0 = vbb, h1 = 0.f, h2 = 0.f, h3 = 0.f;
#pragma unroll
    for (int kq = 0; kq < 16; ++kq) {
      const float4 wv =
          *reinterpret_cast<const float4*>(&sWbT[j * 68 + kq * 4]);
      h0 += rdlane_f(t, kq * 4 + 0) * wv.x;
      h1 += rdlane_f(t, kq * 4 + 1) * wv.y;
      h2 += rdlane_f(t, kq * 4 + 2) * wv.z;
      h3 += rdlane_f(t, kq * 4 + 3) * wv.w;
    }
    float h = fmaxf(h0 + h1 + h2 + h3, 0.f);
    h1b[(size_t)n * 64 + j] = f2bf(h);
  }
}

// Fused conv2 + MLP2.  Wave per node.  Lane = (edge-slot q, channel-quad m):
// 4 edges processed per iteration, each quarter (16 lanes) gathers one edge's
// h1 row as ushort4 -> 4 independent 128B-line gathers in flight per instr.
__global__ __launch_bounds__(512) void conv2_mlp2_kernel(
    const unsigned short* __restrict__ h1b, const uint4* __restrict__ csr,
    const int* __restrict__ deg, const int* __restrict__ cursor,
    const float* __restrict__ We2, const float* __restrict__ be2,
    const float* __restrict__ W2a, const float* __restrict__ b2a,
    const float* __restrict__ W2b, const float* __restrict__ b2b,
    unsigned short* __restrict__ h2b, int N) {
  __shared__ float sWaT[64 * 68];
  __shared__ float sWbT[64 * 68];
  for (int i = threadIdx.x; i < 4096; i += 512) {
    sWaT[(i & 63) * 68 + (i >> 6)] = W2a[i];  // sWaT[j][k] = Wa[k][j]
    sWbT[(i & 63) * 68 + (i >> 6)] = W2b[i];
  }
  __syncthreads();
  int w = threadIdx.x >> 6, j = threadIdx.x & 63;
  int q = j >> 4;  // edge slot 0..3
  int m = j & 15;  // channel quad: channels m*4 .. m*4+3
  // per-lane edge-linear weights for this lane's 4 channels
  float4 ew0 = *reinterpret_cast<const float4*>(&We2[0 * 64 + m * 4]);
  float4 ew1 = *reinterpret_cast<const float4*>(&We2[1 * 64 + m * 4]);
  float4 ew2 = *reinterpret_cast<const float4*>(&We2[2 * 64 + m * 4]);
  float4 ew3 = *reinterpret_cast<const float4*>(&We2[3 * 64 + m * 4]);
  float4 eb = *reinterpret_cast<const float4*>(&be2[m * 4]);
  float vba = b2a[j], vbb = b2b[j];
  int wid = blockIdx.x * 8 + w;
  int nw = gridDim.x * 8;
  for (int n = wid; n < N; n += nw) {
    int end = cursor[n];
    int start = end - deg[n];
    float acc0 = 0.f, acc1 = 0.f, acc2 = 0.f, acc3 = 0.f;
    for (int base = start; base < end; base += 64) {
      int cnt = min(64, end - base);
      int sl = 0;
      int ax = 0, ay = 0;
      if (base + j < end) {
        uint4 u = csr[base + j];  // coalesced 16B
        sl = (int)u.x;
        ax = (int)u.y;
        ay = (int)u.z;
      }
      int ngrp = (cnt + 3) >> 2;
      for (int it = 0; it < ngrp; ++it) {  // wave-uniform trip count
        int lane = it * 4 + q;             // per-lane edge index in chunk
        int s = __shfl(sl, lane);
        unsigned uax = (unsigned)__shfl(ax, lane);
        unsigned uay = (unsigned)__shfl(ay, lane);
        // gather this edge's h1 channels m*4..m*4+3 (16 lanes -> one 128B line)
        ushort4 hv =
            *reinterpret_cast<const ushort4*>(&h1b[(size_t)s * 64 + m * 4]);
        float a0 = __uint_as_float(uax << 16);
        float a1 = __uint_as_float(uax & 0xffff0000u);
        float a2 = __uint_as_float(uay << 16);
        float a3 = __uint_as_float(uay & 0xffff0000u);
        float e0 = eb.x + a0 * ew0.x + a1 * ew1.x + a2 * ew2.x + a3 * ew3.x;
        float e1 = eb.y + a0 * ew0.y + a1 * ew1.y + a2 * ew2.y + a3 * ew3.y;
        float e2 = eb.z + a0 * ew0.z + a1 * ew1.z + a2 * ew2.z + a3 * ew3.z;
        float e3 = eb.w + a0 * ew0.w + a1 * ew1.w + a2 * ew2.w + a3 * ew3.w;
        if (lane < cnt) {  // per-lane validity
          acc0 += fmaxf(bf2f(hv.x) + e0, 0.f);
          acc1 += fmaxf(bf2f(hv.y) + e1, 0.f);
          acc2 += fmaxf(bf2f(hv.z) + e2, 0.f);
          acc3 += fmaxf(bf2f(hv.w) + e3, 0.f);
        }
      }
    }
    // combine the 4 quarters (lanes differing in bits 4 and 5)
    acc0 += __shfl_xor(acc0, 16);
    acc0 += __shfl_xor(acc0, 32);
    acc1 += __shfl_xor(acc1, 16);
    acc1 += __shfl_xor(acc1, 32);
    acc2 += __shfl_xor(acc2, 16);
    acc2 += __shfl_xor(acc2, 32);
    acc3 += __shfl_xor(acc3, 16);
    acc3 += __shfl_xor(acc3, 32);
    // self term for this lane's channels
    ushort4 sv =
        *reinterpret_cast<const ushort4*>(&h1b[(size_t)n * 64 + m * 4]);
    float p0 = acc0 + bf2f(sv.x);
    float p1 = acc1 + bf2f(sv.y);
    float p2 = acc2 + bf2f(sv.z);
    float p3 = acc3 + bf2f(sv.w);
    // layer A: t_j = ba_j + sum_k p_k Wa[k][j]; p_{kq*4+f} = comp f of lane kq
    float t0 = vba, t1 = 0.f, t2 = 0.f, t3 = 0.f;
#pragma unroll
    for (int kq = 0; kq < 16; ++kq) {
      const float4 wv =
          *reinterpret_cast<const float4*>(&sWaT[j * 68 + kq * 4]);
      t0 += rdlane_f(p0, kq) * wv.x;
      t1 += rdlane_f(p1, kq) * wv.y;
      t2 += rdlane_f(p2, kq) * wv.z;
      t3 += rdlane_f(p3, kq) * wv.w;
    }
    float t = fmaxf(t0 + t1 + t2 + t3, 0.f);  // lane = channel
    // layer B
    float h0 = vbb, h1 = 0.f, h2 = 0.f, h3 = 0.f;
#pragma unroll
    for (int kq = 0; kq < 16; ++kq) {
      const float4 wv =
          *reinterpret_cast<const float4*>(&sWbT[j * 68 + kq * 4]);
      h0 += rdlane_f(t, kq * 4 + 0) * wv.x;
      h1 += rdlane_f(t, kq * 4 + 1) * wv.y;
      h2 += rdlane_f(t, kq * 4 + 2) * wv.z;
      h3 += rdlane_f(t, kq * 4 + 3) * wv.w;
    }
    float h = fmaxf(h0 + h1 + h2 + h3, 0.f);
    h2b[(size_t)n * 64 + j] = f2bf(h);
  }
}

__global__ __launch_bounds__(64) void pool_fc_kernel(
    const unsigned short* __restrict__ h2b, const int* __restrict__ batch,
    const float* __restrict__ Wfc, const float* __restrict__ bfc,
    float* __restrict__ out, int N, int G) {
  int g = blockIdx.x;
  int j = threadIdx.x;  // 0..63
  int q = j >> 4;       // row slot
  int m = j & 15;       // channel quad
  int lo = 0, hi = N;
  while (lo < hi) {
    int mid = (lo + hi) >> 1;
    if (batch[mid] < g) lo = mid + 1; else hi = mid;
  }
  int start = lo;
  lo = start; hi = N;
  while (lo < hi) {
    int mid = (lo + hi) >> 1;
    if (batch[mid] < g + 1) lo = mid + 1; else hi = mid;
  }
  int end = lo;
  int cnt = end - start;
  float s0 = 0.f, s1 = 0.f, s2 = 0.f, s3 = 0.f;
  int ngrp = (cnt + 3) >> 2;
  for (int it = 0; it < ngrp; ++it) {
    int r = start + it * 4 + q;
    if (r < end) {
      ushort4 hv =
          *reinterpret_cast<const ushort4*>(&h2b[(size_t)r * 64 + m * 4]);
      s0 += bf2f(hv.x);
      s1 += bf2f(hv.y);
      s2 += bf2f(hv.z);
      s3 += bf2f(hv.w);
    }
  }
  s0 += __shfl_xor(s0, 16); s0 += __shfl_xor(s0, 32);
  s1 += __shfl_xor(s1, 16); s1 += __shfl_xor(s1, 32);
  s2 += __shfl_xor(s2, 16); s2 += __shfl_xor(s2, 32);
  s3 += __shfl_xor(s3, 16); s3 += __shfl_xor(s3, 32);
  float inv = 1.f / fmaxf((float)cnt, 1.f);
  __shared__ float spool[64];
  if (q == 0) {
    spool[m * 4 + 0] = s0 * inv;
    spool[m * 4 + 1] = s1 * inv;
    spool[m * 4 + 2] = s2 * inv;
    spool[m * 4 + 3] = s3 * inv;
  }
  __syncthreads();
  if (j < 12) {
    float o = bfc[j];
#pragma unroll
    for (int k = 0; k < 64; ++k) o += spool[k] * Wfc[k * 12 + j];
    out[(size_t)g * 12 + j] = o;
  }
}

extern "C" void kernel_launch(void* const* d_in, const int* in_sizes, int n_in,
                              void* d_out, int out_size, void* d_ws,
                              size_t ws_size, hipStream_t stream) {
  const float* x   = (const float*)d_in[0];
  const float* ea  = (const float*)d_in[1];
  const float* We1 = (const float*)d_in[2];
  const float* be1 = (const float*)d_in[3];
  const float* We2 = (const float*)d_in[4];
  const float* be2 = (const float*)d_in[5];
  const float* W1a = (const float*)d_in[6];
  const float* b1a = (const float*)d_in[7];
  const float* W1b = (const float*)d_in[8];
  const float* b1b = (const float*)d_in[9];
  const float* W2a = (const float*)d_in[10];
  const float* b2a = (const float*)d_in[11];
  const float* W2b = (const float*)d_in[12];
  const float* b2b = (const float*)d_in[13];
  const float* Wfc = (const float*)d_in[14];
  const float* bfc = (const float*)d_in[15];
  const int* eidx  = (const int*)d_in[16];
  const int* batch = (const int*)d_in[17];

  int N = in_sizes[0] / 7;
  int E = in_sizes[1] / 4;
  int G = out_size / 12;
  const int* srcIdx = eidx;
  const int* dstIdx = eidx + E;

  char* ws = (char*)d_ws;
  int*   deg      = (int*)ws;             ws += (size_t)N * 4;
  int*   cursor   = (int*)ws;             ws += (size_t)N * 4;
  int*   blockSum = (int*)ws;             ws += 4096;
  int*   blockOff = (int*)ws;             ws += 4096;
  uint4* csr      = (uint4*)ws;           ws += (size_t)E * 16;
  unsigned short* h1b = (unsigned short*)ws; ws += (size_t)N * 64 * 2;
  unsigned short* h2b = (unsigned short*)ws; /* += N*64*2 */
  // total ~ 0.8 + 25.6 + 12.8 + 12.8 MB ~= 52 MB

  int nb = (N + CHUNK - 1) / CHUNK;

  hipMemsetAsync(deg, 0, (size_t)N * 4, stream);
  hist_kernel<<<((E + 3) / 4 + 255) / 256, 256, 0, stream>>>(dstIdx, deg, E);
  scan1_kernel<<<nb, 256, 0, stream>>>(deg, cursor, blockSum, N);
  scan2_kernel<<<1, 256, 0, stream>>>(blockSum, blockOff, nb);
  scan3_kernel<<<(N + 255) / 256, 256, 0, stream>>>(cursor, blockOff, N);
  scatter_kernel<<<(E + 255) / 256, 256, 0, stream>>>(srcIdx, dstIdx, ea,
                                                      cursor, csr, E);
  conv1_mlp1_kernel<<<1024, 512, 0, stream>>>(x, csr, We1, be1, deg, cursor,
                                              W1a, b1a, W1b, b1b, h1b, N);
  conv2_mlp2_kernel<<<1024, 512, 0, stream>>>(h1b, csr, deg, cursor, We2, be2,
                                              W2a, b2a, W2b, b2b, h2b, N);
  pool_fc_kernel<<<G, 64, 0, stream>>>(h2b, batch, Wfc, bfc, (float*)d_out, N,
                                       G);
}

// Round 10
// 303.652 us; speedup vs baseline: 1.8894x; 1.4592x over previous
//
#include <hip/hip_runtime.h>
#include <hip/hip_bf16.h>

// ---------------------------------------------------------------------------
// GINE x2 + mean-pool + FC.
// CSR build (hist/scan/scatter, uint4 entries {src, bf16x4 ea}) ->
// agg1 (thread/node, 7ch)  -> p1 f32[N][8]
// mlp_mfma<8>  (MFMA 16x16x32 bf16, both layers) -> h1 bf16[N][64]
// agg2 (wave/node, quarter-parallel ushort4 gathers, NO mlp) -> p2 bf16[N][64]
// mlp_mfma<64> -> h2 bf16[N][64]
// pool_fc (block/graph, binary search on sorted batch)
// ---------------------------------------------------------------------------

#define CHUNK 1024

typedef __attribute__((ext_vector_type(8))) short bf16x8;
typedef __attribute__((ext_vector_type(4))) float f32x4;

__device__ __forceinline__ float bf2f(unsigned short u) {
  return __uint_as_float(((unsigned)u) << 16);
}
__device__ __forceinline__ unsigned short f2bf(float f) {
  __hip_bfloat16 hb = __float2bfloat16(f);
  return *reinterpret_cast<unsigned short*>(&hb);
}

__global__ __launch_bounds__(256) void hist_kernel(
    const int* __restrict__ dstIdx, int* __restrict__ deg, int E) {
  int i = blockIdx.x * 256 + threadIdx.x;
  int e0 = i * 4;
  if (e0 + 3 < E) {
    int4 d = reinterpret_cast<const int4*>(dstIdx)[i];
    atomicAdd(&deg[d.x], 1);
    atomicAdd(&deg[d.y], 1);
    atomicAdd(&deg[d.z], 1);
    atomicAdd(&deg[d.w], 1);
  } else {
    for (int e = e0; e < E; ++e) atomicAdd(&deg[dstIdx[e]], 1);
  }
}

__global__ __launch_bounds__(256) void scan1_kernel(
    const int* __restrict__ deg, int* __restrict__ cursor,
    int* __restrict__ blockSum, int N) {
  __shared__ int sd[256];
  int t = threadIdx.x;
  int base = blockIdx.x * CHUNK + t * 4;
  int v0 = (base + 0 < N) ? deg[base + 0] : 0;
  int v1 = (base + 1 < N) ? deg[base + 1] : 0;
  int v2 = (base + 2 < N) ? deg[base + 2] : 0;
  int v3 = (base + 3 < N) ? deg[base + 3] : 0;
  int ts = v0 + v1 + v2 + v3;
  sd[t] = ts;
  __syncthreads();
  for (int off = 1; off < 256; off <<= 1) {
    int xv = (t >= off) ? sd[t - off] : 0;
    __syncthreads();
    sd[t] += xv;
    __syncthreads();
  }
  int excl = sd[t] - ts;
  if (t == 255) blockSum[blockIdx.x] = sd[255];
  if (base + 0 < N) cursor[base + 0] = excl;
  if (base + 1 < N) cursor[base + 1] = excl + v0;
  if (base + 2 < N) cursor[base + 2] = excl + v0 + v1;
  if (base + 3 < N) cursor[base + 3] = excl + v0 + v1 + v2;
}

__global__ __launch_bounds__(256) void scan2_kernel(
    const int* __restrict__ blockSum, int* __restrict__ blockOff, int nb) {
  __shared__ int sd[256];
  int t = threadIdx.x;
  int base = t * 4;
  int v0 = (base + 0 < nb) ? blockSum[base + 0] : 0;
  int v1 = (base + 1 < nb) ? blockSum[base + 1] : 0;
  int v2 = (base + 2 < nb) ? blockSum[base + 2] : 0;
  int v3 = (base + 3 < nb) ? blockSum[base + 3] : 0;
  int ts = v0 + v1 + v2 + v3;
  sd[t] = ts;
  __syncthreads();
  for (int off = 1; off < 256; off <<= 1) {
    int xv = (t >= off) ? sd[t - off] : 0;
    __syncthreads();
    sd[t] += xv;
    __syncthreads();
  }
  int excl = sd[t] - ts;
  if (base + 0 < nb) blockOff[base + 0] = excl;
  if (base + 1 < nb) blockOff[base + 1] = excl + v0;
  if (base + 2 < nb) blockOff[base + 2] = excl + v0 + v1;
  if (base + 3 < nb) blockOff[base + 3] = excl + v0 + v1 + v2;
}

__global__ __launch_bounds__(256) void scan3_kernel(
    int* __restrict__ cursor, const int* __restrict__ blockOff, int N) {
  int i = blockIdx.x * 256 + threadIdx.x;
  if (i < N) cursor[i] += blockOff[i >> 10];  // log2(CHUNK)
}

__global__ __launch_bounds__(256) void scatter_kernel(
    const int* __restrict__ srcIdx, const int* __restrict__ dstIdx,
    const float* __restrict__ ea, int* __restrict__ cursor,
    uint4* __restrict__ csr, int E) {
  int e = blockIdx.x * 256 + threadIdx.x;
  if (e >= E) return;
  float4 a = reinterpret_cast<const float4*>(ea)[e];
  uint4 v;
  v.x = (unsigned)srcIdx[e];
  v.y = (unsigned)f2bf(a.x) | ((unsigned)f2bf(a.y) << 16);
  v.z = (unsigned)f2bf(a.z) | ((unsigned)f2bf(a.w) << 16);
  v.w = 0;
  int pos = atomicAdd(&cursor[dstIdx[e]], 1);
  csr[pos] = v;  // single 16B scattered store
}

// agg1: thread per node; 7-channel gather-accumulate; writes p1 = x + agg
// (f32, stride 8, slot 7 = 0).
__global__ __launch_bounds__(256) void agg1_kernel(
    const float* __restrict__ x, const uint4* __restrict__ csr,
    const float* __restrict__ We1, const float* __restrict__ be1,
    const int* __restrict__ deg, const int* __restrict__ cursor,
    float* __restrict__ p1, int N) {
  int n = blockIdx.x * 256 + threadIdx.x;
  if (n >= N) return;
  float w[28], b[7];
#pragma unroll
  for (int i = 0; i < 28; ++i) w[i] = We1[i];
#pragma unroll
  for (int i = 0; i < 7; ++i) b[i] = be1[i];
  int end = cursor[n];
  int start = end - deg[n];
  float acc[7];
#pragma unroll
  for (int c = 0; c < 7; ++c) acc[c] = 0.f;
  for (int i = start; i < end; ++i) {
    uint4 u = csr[i];
    int s = (int)u.x;
    float a0 = __uint_as_float(u.y << 16);
    float a1 = __uint_as_float(u.y & 0xffff0000u);
    float a2 = __uint_as_float(u.z << 16);
    float a3 = __uint_as_float(u.z & 0xffff0000u);
    const float* xs = x + (size_t)s * 7;
#pragma unroll
    for (int c = 0; c < 7; ++c) {
      float v = b[c] + a0 * w[c] + a1 * w[7 + c] + a2 * w[14 + c] +
                a3 * w[21 + c] + xs[c];
      acc[c] += fmaxf(v, 0.f);
    }
  }
  const float* xn = x + (size_t)n * 7;
#pragma unroll
  for (int c = 0; c < 7; ++c) p1[(size_t)n * 8 + c] = acc[c] + xn[c];
  p1[(size_t)n * 8 + 7] = 0.f;
}

// agg2: wave per node, quarter-parallel (lane = edge-slot q, channel-quad m).
// No MLP, no LDS -> low VGPR, high occupancy.  Writes p2 bf16[N][64].
__global__ __launch_bounds__(256) void agg2_kernel(
    const unsigned short* __restrict__ h1b, const uint4* __restrict__ csr,
    const int* __restrict__ deg, const int* __restrict__ cursor,
    const float* __restrict__ We2, const float* __restrict__ be2,
    unsigned short* __restrict__ p2b, int N) {
  int w = threadIdx.x >> 6, j = threadIdx.x & 63;
  int q = j >> 4;  // edge slot 0..3
  int m = j & 15;  // channel quad
  float4 ew0 = *reinterpret_cast<const float4*>(&We2[0 * 64 + m * 4]);
  float4 ew1 = *reinterpret_cast<const float4*>(&We2[1 * 64 + m * 4]);
  float4 ew2 = *reinterpret_cast<const float4*>(&We2[2 * 64 + m * 4]);
  float4 ew3 = *reinterpret_cast<const float4*>(&We2[3 * 64 + m * 4]);
  float4 eb = *reinterpret_cast<const float4*>(&be2[m * 4]);
  int wid = blockIdx.x * 4 + w;
  int nw = gridDim.x * 4;
  for (int n = wid; n < N; n += nw) {
    int end = cursor[n];
    int start = end - deg[n];
    float acc0 = 0.f, acc1 = 0.f, acc2 = 0.f, acc3 = 0.f;
    for (int base = start; base < end; base += 64) {
      int cnt = min(64, end - base);
      int sl = 0;
      int ax = 0, ay = 0;
      if (base + j < end) {
        uint4 u = csr[base + j];  // coalesced 16B
        sl = (int)u.x;
        ax = (int)u.y;
        ay = (int)u.z;
      }
      int ngrp = (cnt + 3) >> 2;
      for (int it = 0; it < ngrp; ++it) {  // wave-uniform trip count
        int lane = it * 4 + q;
        int s = __shfl(sl, lane);
        unsigned uax = (unsigned)__shfl(ax, lane);
        unsigned uay = (unsigned)__shfl(ay, lane);
        ushort4 hv =
            *reinterpret_cast<const ushort4*>(&h1b[(size_t)s * 64 + m * 4]);
        float a0 = __uint_as_float(uax << 16);
        float a1 = __uint_as_float(uax & 0xffff0000u);
        float a2 = __uint_as_float(uay << 16);
        float a3 = __uint_as_float(uay & 0xffff0000u);
        float e0 = eb.x + a0 * ew0.x + a1 * ew1.x + a2 * ew2.x + a3 * ew3.x;
        float e1 = eb.y + a0 * ew0.y + a1 * ew1.y + a2 * ew2.y + a3 * ew3.y;
        float e2 = eb.z + a0 * ew0.z + a1 * ew1.z + a2 * ew2.z + a3 * ew3.z;
        float e3 = eb.w + a0 * ew0.w + a1 * ew1.w + a2 * ew2.w + a3 * ew3.w;
        if (lane < cnt) {
          acc0 += fmaxf(bf2f(hv.x) + e0, 0.f);
          acc1 += fmaxf(bf2f(hv.y) + e1, 0.f);
          acc2 += fmaxf(bf2f(hv.z) + e2, 0.f);
          acc3 += fmaxf(bf2f(hv.w) + e3, 0.f);
        }
      }
    }
    acc0 += __shfl_xor(acc0, 16); acc0 += __shfl_xor(acc0, 32);
    acc1 += __shfl_xor(acc1, 16); acc1 += __shfl_xor(acc1, 32);
    acc2 += __shfl_xor(acc2, 16); acc2 += __shfl_xor(acc2, 32);
    acc3 += __shfl_xor(acc3, 16); acc3 += __shfl_xor(acc3, 32);
    ushort4 sv =
        *reinterpret_cast<const ushort4*>(&h1b[(size_t)n * 64 + m * 4]);
    if (q == 0) {  // one quarter writes the (reduced) row
      ushort4 o;
      o.x = f2bf(acc0 + bf2f(sv.x));
      o.y = f2bf(acc1 + bf2f(sv.y));
      o.z = f2bf(acc2 + bf2f(sv.z));
      o.w = f2bf(acc3 + bf2f(sv.w));
      *reinterpret_cast<ushort4*>(&p2b[(size_t)n * 64 + m * 4]) = o;
    }
  }
}

// Fused 2-layer MLP via MFMA 16x16x32 bf16.  KIN=8: input f32[N][8]
// (rows 7..31 of Wa zero-padded); KIN=64: input bf16[N][64].
// Layouts (m89-verified): A row=lane&15, k=(lane>>4)*8+i; B col=lane&15,
// k=(lane>>4)*8+i; C/D col=lane&15, row=(lane>>4)*4+reg.
template <int KIN>
__global__ __launch_bounds__(256) void mlp_mfma_kernel(
    const void* __restrict__ pin, const float* __restrict__ Wa,
    const float* __restrict__ ba, const float* __restrict__ Wb,
    const float* __restrict__ bb, unsigned short* __restrict__ hout, int N) {
  __shared__ unsigned short t_lds[4][16 * 72];  // row stride 144B (9x16B)
  int w = threadIdx.x >> 6, l = threadIdx.x & 63;
  int lr = l & 15, lq = l >> 4;
  constexpr int KSA = (KIN == 8) ? 1 : 2;
  constexpr int VROWS = (KIN == 8) ? 7 : 64;
  bf16x8 wa[2][4], wb[2][4];
#pragma unroll
  for (int ks = 0; ks < KSA; ++ks)
#pragma unroll
    for (int c = 0; c < 4; ++c) {
      bf16x8 f;
#pragma unroll
      for (int r = 0; r < 8; ++r) {
        int row = ks * 32 + lq * 8 + r;
        float v = (row < VROWS) ? Wa[row * 64 + c * 16 + lr] : 0.f;
        f[r] = (short)f2bf(v);
      }
      wa[ks][c] = f;
    }
#pragma unroll
  for (int ks = 0; ks < 2; ++ks)
#pragma unroll
    for (int c = 0; c < 4; ++c) {
      bf16x8 f;
#pragma unroll
      for (int r = 0; r < 8; ++r)
        f[r] = (short)f2bf(Wb[(ks * 32 + lq * 8 + r) * 64 + c * 16 + lr]);
      wb[ks][c] = f;
    }
  float vba[4], vbb[4];
#pragma unroll
  for (int c = 0; c < 4; ++c) {
    vba[c] = ba[c * 16 + lr];
    vbb[c] = bb[c * 16 + lr];
  }
  unsigned short* tl = t_lds[w];
  int ntiles = (N + 15) >> 4;
  for (int tile = blockIdx.x * 4 + w; tile < ntiles; tile += gridDim.x * 4) {
    int n0 = tile << 4;
    int arow = n0 + lr;
    // stage A-frags for layer A
    bf16x8 af0, af1;
#pragma unroll
    for (int r = 0; r < 8; ++r) { af0[r] = 0; af1[r] = 0; }
    if (KIN == 8) {
      if (lq == 0 && arow < N) {
        const float* pr = (const float*)pin + (size_t)arow * 8;
#pragma unroll
        for (int r = 0; r < 8; ++r) af0[r] = (short)f2bf(pr[r]);
      }
    } else {
      if (arow < N) {
        const unsigned short* pr =
            (const unsigned short*)pin + (size_t)arow * 64 + lq * 8;
        af0 = *(const bf16x8*)(pr);
        af1 = *(const bf16x8*)(pr + 32);
      }
    }
    // layer A
    f32x4 accA[4];
#pragma unroll
    for (int c = 0; c < 4; ++c) {
      f32x4 a = {0.f, 0.f, 0.f, 0.f};
      a = __builtin_amdgcn_mfma_f32_16x16x32_bf16(af0, wa[0][c], a, 0, 0, 0);
      if (KSA == 2)
        a = __builtin_amdgcn_mfma_f32_16x16x32_bf16(af1, wa[1][c], a, 0, 0, 0);
      accA[c] = a;
    }
    // bias + relu -> t in LDS (C-layout write, A-layout read)
#pragma unroll
    for (int c = 0; c < 4; ++c)
#pragma unroll
      for (int r = 0; r < 4; ++r) {
        float v = fmaxf(accA[c][r] + vba[c], 0.f);
        tl[(lq * 4 + r) * 72 + c * 16 + lr] = f2bf(v);
      }
    bf16x8 tf0 = *(const bf16x8*)&tl[lr * 72 + lq * 8];
    bf16x8 tf1 = *(const bf16x8*)&tl[lr * 72 + 32 + lq * 8];
    // layer B + bias + relu + store
#pragma unroll
    for (int c = 0; c < 4; ++c) {
      f32x4 a = {0.f, 0.f, 0.f, 0.f};
      a = __builtin_amdgcn_mfma_f32_16x16x32_bf16(tf0, wb[0][c], a, 0, 0, 0);
      a = __builtin_amdgcn_mfma_f32_16x16x32_bf16(tf1, wb[1][c], a, 0, 0, 0);
#pragma unroll
      for (int r = 0; r < 4; ++r) {
        int row = n0 + lq * 4 + r;
        if (row < N) {
          float v = fmaxf(a[r] + vbb[c], 0.f);
          hout[(size_t)row * 64 + c * 16 + lr] = f2bf(v);
        }
      }
    }
  }
}

__global__ __launch_bounds__(64) void pool_fc_kernel(
    const unsigned short* __restrict__ h2b, const int* __restrict__ batch,
    const float* __restrict__ Wfc, const float* __restrict__ bfc,
    float* __restrict__ out, int N, int G) {
  int g = blockIdx.x;
  int j = threadIdx.x;  // 0..63
  int q = j >> 4;
  int m = j & 15;
  int lo = 0, hi = N;
  while (lo < hi) {
    int mid = (lo + hi) >> 1;
    if (batch[mid] < g) lo = mid + 1; else hi = mid;
  }
  int start = lo;
  lo = start; hi = N;
  while (lo < hi) {
    int mid = (lo + hi) >> 1;
    if (batch[mid] < g + 1) lo = mid + 1; else hi = mid;
  }
  int end = lo;
  int cnt = end - start;
  float s0 = 0.f, s1 = 0.f, s2 = 0.f, s3 = 0.f;
  int ngrp = (cnt + 3) >> 2;
  for (int it = 0; it < ngrp; ++it) {
    int r = start + it * 4 + q;
    if (r < end) {
      ushort4 hv =
          *reinterpret_cast<const ushort4*>(&h2b[(size_t)r * 64 + m * 4]);
      s0 += bf2f(hv.x);
      s1 += bf2f(hv.y);
      s2 += bf2f(hv.z);
      s3 += bf2f(hv.w);
    }
  }
  s0 += __shfl_xor(s0, 16); s0 += __shfl_xor(s0, 32);
  s1 += __shfl_xor(s1, 16); s1 += __shfl_xor(s1, 32);
  s2 += __shfl_xor(s2, 16); s2 += __shfl_xor(s2, 32);
  s3 += __shfl_xor(s3, 16); s3 += __shfl_xor(s3, 32);
  float inv = 1.f / fmaxf((float)cnt, 1.f);
  __shared__ float spool[64];
  if (q == 0) {
    spool[m * 4 + 0] = s0 * inv;
    spool[m * 4 + 1] = s1 * inv;
    spool[m * 4 + 2] = s2 * inv;
    spool[m * 4 + 3] = s3 * inv;
  }
  __syncthreads();
  if (j < 12) {
    float o = bfc[j];
#pragma unroll
    for (int k = 0; k < 64; ++k) o += spool[k] * Wfc[k * 12 + j];
    out[(size_t)g * 12 + j] = o;
  }
}

extern "C" void kernel_launch(void* const* d_in, const int* in_sizes, int n_in,
                              void* d_out, int out_size, void* d_ws,
                              size_t ws_size, hipStream_t stream) {
  const float* x   = (const float*)d_in[0];
  const float* ea  = (const float*)d_in[1];
  const float* We1 = (const float*)d_in[2];
  const float* be1 = (const float*)d_in[3];
  const float* We2 = (const float*)d_in[4];
  const float* be2 = (const float*)d_in[5];
  const float* W1a = (const float*)d_in[6];
  const float* b1a = (const float*)d_in[7];
  const float* W1b = (const float*)d_in[8];
  const float* b1b = (const float*)d_in[9];
  const float* W2a = (const float*)d_in[10];
  const float* b2a = (const float*)d_in[11];
  const float* W2b = (const float*)d_in[12];
  const float* b2b = (const float*)d_in[13];
  const float* Wfc = (const float*)d_in[14];
  const float* bfc = (const float*)d_in[15];
  const int* eidx  = (const int*)d_in[16];
  const int* batch = (const int*)d_in[17];

  int N = in_sizes[0] / 7;
  int E = in_sizes[1] / 4;
  int G = out_size / 12;
  const int* srcIdx = eidx;
  const int* dstIdx = eidx + E;

  char* ws = (char*)d_ws;
  int*   deg      = (int*)ws;             ws += (size_t)N * 4;
  int*   cursor   = (int*)ws;             ws += (size_t)N * 4;
  int*   blockSum = (int*)ws;             ws += 4096;
  int*   blockOff = (int*)ws;             ws += 4096;
  uint4* csr      = (uint4*)ws;           ws += (size_t)E * 16;
  float* p1       = (float*)ws;           ws += (size_t)N * 8 * 4;
  unsigned short* h1b = (unsigned short*)ws; ws += (size_t)N * 64 * 2;
  unsigned short* p2b = (unsigned short*)ws; ws += (size_t)N * 64 * 2;
  unsigned short* h2b = (unsigned short*)ws; /* += N*64*2 */
  // total ~ 0.8 + 25.6 + 3.2 + 3*12.8 ~= 68 MB

  int nb = (N + CHUNK - 1) / CHUNK;
  int ntiles = (N + 15) / 16;
  int mlpBlocks = (ntiles + 3) / 4;
  if (mlpBlocks > 1024) mlpBlocks = 1024;  // grid-stride

  hipMemsetAsync(deg, 0, (size_t)N * 4, stream);
  hist_kernel<<<((E + 3) / 4 + 255) / 256, 256, 0, stream>>>(dstIdx, deg, E);
  scan1_kernel<<<nb, 256, 0, stream>>>(deg, cursor, blockSum, N);
  scan2_kernel<<<1, 256, 0, stream>>>(blockSum, blockOff, nb);
  scan3_kernel<<<(N + 255) / 256, 256, 0, stream>>>(cursor, blockOff, N);
  scatter_kernel<<<(E + 255) / 256, 256, 0, stream>>>(srcIdx, dstIdx, ea,
                                                      cursor, csr, E);
  agg1_kernel<<<(N + 255) / 256, 256, 0, stream>>>(x, csr, We1, be1, deg,
                                                   cursor, p1, N);
  mlp_mfma_kernel<8><<<mlpBlocks, 256, 0, stream>>>(p1, W1a, b1a, W1b, b1b,
                                                    h1b, N);
  agg2_kernel<<<2048, 256, 0, stream>>>(h1b, csr, deg, cursor, We2, be2, p2b,
                                        N);
  mlp_mfma_kernel<64><<<mlpBlocks, 256, 0, stream>>>(p2b, W2a, b2a, W2b, b2b,
                                                     h2b, N);
  pool_fc_kernel<<<G, 64, 0, stream>>>(h2b, batch, Wfc, bfc, (float*)d_out, N,
                                       G);
}